// Round 1
// baseline (417.128 us; speedup 1.0000x reference)
//
#include <hip/hip_runtime.h>

// DCT-domain 2x upsampling:  out[b,c] = mask[c] * U @ X[b,c] @ U^T
// with U[n][h] = sum_{k<64} DH2[k][n] * DH[k][h]   (128x64, fixed)
// Derivation: 2D ortho DCT-64, zero-pad to 128, ortho IDCT-128 == U X U^T,
// and V = DW^T @ DW2[:64,:] == U^T because DH==DW, DH2==DW2.

#define NSLICES 4096  // 16 * 256

// ---------------------------------------------------------------------------
// Build Ut[h][n] = U[n][h] into workspace (recomputed every call; ws is
// re-poisoned by the harness). 8192 entries, 64-term cosine sum each.
// cospif with exactly-representable integer/2^k arguments -> ~1e-7 per term.
// ---------------------------------------------------------------------------
__global__ void build_ut(float* __restrict__ ut) {
    const int idx = blockIdx.x * 256 + threadIdx.x;  // 0..8191
    const int h = idx >> 7;    // 0..63
    const int n = idx & 127;   // 0..127
    const float s0 = 0.125f;                 // sqrt(1/64)
    const float sk = 0.17677669529663687f;   // sqrt(2/64)
    const float t0 = 0.088388347648318447f;  // sqrt(1/128)
    const float tk = 0.125f;                 // sqrt(2/128)
    float acc = s0 * t0;  // k = 0 term (cos terms are 1)
    #pragma unroll 4
    for (int k = 1; k < 64; ++k) {
        float a = cospif((float)((2 * h + 1) * k) * (1.0f / 128.0f));
        float b = cospif((float)((2 * n + 1) * k) * (1.0f / 256.0f));
        acc = fmaf(sk * tk * a, b, acc);
    }
    ut[h * 128 + n] = acc;
}

// ---------------------------------------------------------------------------
// Fused per-slice kernel. One block = one (b,c) slice.
//   LDS: sU = Ut[64][128] (32KB), sX = X[64][64] (16KB), sT = T^T[64][128] (32KB)
//   Stage 1: T[n][w] = sum_h sU[h][n] * sX[h][w]        (store transposed in sT)
//   Stage 2: out[n][m] = sum_w sT[w][n] * sU[w][m]
// 256 threads; stage-1 tile 4(w)x8(n), stage-2 tile 8(n)x8(m).
// 80KB LDS -> 2 blocks/CU (8 waves/CU, 2/SIMD) — enough for FMA-chain ILP.
// ---------------------------------------------------------------------------
__global__ __launch_bounds__(256, 2)
void dct_fsr(const float* __restrict__ x, const float* __restrict__ mask,
             const float* __restrict__ ut, float* __restrict__ out) {
    __shared__ float sU[64 * 128];
    __shared__ float sX[64 * 64];
    __shared__ float sT[64 * 128];

    const int tid = threadIdx.x;
    const int slice = blockIdx.x;             // b*256 + c
    const float mval = mask[slice & 255];     // per-channel scalar

    // ---- load X (mask folded in) and Ut into LDS, fully coalesced float4 ----
    {
        const float4* xg = (const float4*)(x + (size_t)slice * 4096);
        float4* sX4 = (float4*)sX;
        #pragma unroll
        for (int r = 0; r < 4; ++r) {
            float4 v = xg[r * 256 + tid];
            v.x *= mval; v.y *= mval; v.z *= mval; v.w *= mval;
            sX4[r * 256 + tid] = v;
        }
        const float4* ug = (const float4*)ut;
        float4* sU4 = (float4*)sU;
        #pragma unroll
        for (int r = 0; r < 8; ++r)
            sU4[r * 256 + tid] = ug[r * 256 + tid];
    }
    __syncthreads();

    // ---- stage 1: T = U @ X  (write T transposed: sT[w][n]) ----
    {
        const int n0 = (tid & 15) * 8;   // 16 x 8 = 128 n
        const int w0 = (tid >> 4) * 4;   // 16 x 4 = 64  w
        float acc[4][8];
        #pragma unroll
        for (int j = 0; j < 4; ++j)
            #pragma unroll
            for (int i = 0; i < 8; ++i) acc[j][i] = 0.0f;

        #pragma unroll 4
        for (int h = 0; h < 64; ++h) {
            const float4 u0 = *(const float4*)&sU[h * 128 + n0];
            const float4 u1 = *(const float4*)&sU[h * 128 + n0 + 4];
            const float4 xv = *(const float4*)&sX[h * 64 + w0];
            const float uu[8] = {u0.x, u0.y, u0.z, u0.w, u1.x, u1.y, u1.z, u1.w};
            const float xx[4] = {xv.x, xv.y, xv.z, xv.w};
            #pragma unroll
            for (int j = 0; j < 4; ++j)
                #pragma unroll
                for (int i = 0; i < 8; ++i)
                    acc[j][i] = fmaf(xx[j], uu[i], acc[j][i]);
        }
        #pragma unroll
        for (int j = 0; j < 4; ++j) {
            *(float4*)&sT[(w0 + j) * 128 + n0] =
                make_float4(acc[j][0], acc[j][1], acc[j][2], acc[j][3]);
            *(float4*)&sT[(w0 + j) * 128 + n0 + 4] =
                make_float4(acc[j][4], acc[j][5], acc[j][6], acc[j][7]);
        }
    }
    __syncthreads();

    // ---- stage 2: out = T @ U^T ----
    {
        const int n0 = (tid >> 4) * 8;   // 16 x 8 = 128 n
        const int m0 = (tid & 15) * 8;   // 16 x 8 = 128 m
        float acc[8][8];
        #pragma unroll
        for (int i = 0; i < 8; ++i)
            #pragma unroll
            for (int j = 0; j < 8; ++j) acc[i][j] = 0.0f;

        #pragma unroll 2
        for (int w = 0; w < 64; ++w) {
            const float4 t0v = *(const float4*)&sT[w * 128 + n0];
            const float4 t1v = *(const float4*)&sT[w * 128 + n0 + 4];
            const float4 u0v = *(const float4*)&sU[w * 128 + m0];
            const float4 u1v = *(const float4*)&sU[w * 128 + m0 + 4];
            const float tt[8] = {t0v.x, t0v.y, t0v.z, t0v.w, t1v.x, t1v.y, t1v.z, t1v.w};
            const float uu[8] = {u0v.x, u0v.y, u0v.z, u0v.w, u1v.x, u1v.y, u1v.z, u1v.w};
            #pragma unroll
            for (int i = 0; i < 8; ++i)
                #pragma unroll
                for (int j = 0; j < 8; ++j)
                    acc[i][j] = fmaf(tt[i], uu[j], acc[i][j]);
        }

        float* og = out + (size_t)slice * 16384;  // 128*128
        #pragma unroll
        for (int i = 0; i < 8; ++i) {
            *(float4*)&og[(n0 + i) * 128 + m0] =
                make_float4(acc[i][0], acc[i][1], acc[i][2], acc[i][3]);
            *(float4*)&og[(n0 + i) * 128 + m0 + 4] =
                make_float4(acc[i][4], acc[i][5], acc[i][6], acc[i][7]);
        }
    }
}

extern "C" void kernel_launch(void* const* d_in, const int* in_sizes, int n_in,
                              void* d_out, int out_size, void* d_ws, size_t ws_size,
                              hipStream_t stream) {
    const float* x = (const float*)d_in[0];     // [16,256,64,64] fp32
    const float* mask = (const float*)d_in[1];  // [1,256,1,1] fp32
    float* out = (float*)d_out;                 // [16,256,128,128] fp32
    float* ut = (float*)d_ws;                   // 64*128 floats = 32KB

    build_ut<<<32, 256, 0, stream>>>(ut);
    dct_fsr<<<NSLICES, 256, 0, stream>>>(x, mask, ut, out);
}

// Round 6
// 332.823 us; speedup vs baseline: 1.2533x; 1.2533x over previous
//
#include <hip/hip_runtime.h>

// out[b,c] = mask[c] * (U @ X @ U^T),  U[n][h] = sum_k DH2[k][n]*DH[k][h]  (128x64)
// Reordered as:  R = X @ U^T  (K=w, row-major X feeds MFMA A directly),
//                out = U @ R  (K=h, R staged in LDS as [m][h] hi/lo fp16).
// fp16 2-term split (hi+lo), 3 MFMA passes -> ~2^-22 relative error.

typedef __attribute__((ext_vector_type(8))) _Float16 f16x8;
typedef __attribute__((ext_vector_type(4))) _Float16 f16x4;
typedef __attribute__((ext_vector_type(4))) float f32x4;

#define NSLICES 4096
#define MFMA16(A, B, C) __builtin_amdgcn_mfma_f32_16x16x32_f16((A), (B), (C), 0, 0, 0)

// ---------------------------------------------------------------------------
// Build U in MFMA fragment-dump order, fp16 hi/lo.
// Fragment (tile j=0..7, kk=0..1, hl=0..1) = 512 halfs; lane l holds 8 halfs:
//   value = U[16*j + (l&15)][32*kk + 8*(l>>4) + t],  t = 0..7
// Same table serves stage-1 B (index by m-tile) and stage-2 A (index by n-tile).
// ---------------------------------------------------------------------------
__global__ void build_ut(_Float16* __restrict__ uf) {
    const int idx = blockIdx.x * 256 + threadIdx.x;  // 0..8191
    const int n = idx >> 6;   // 0..127 (U row)
    const int h = idx & 63;   // 0..63  (U col)
    const float s0 = 0.125f;                 // sqrt(1/64)
    const float sk = 0.17677669529663687f;   // sqrt(2/64)
    const float t0 = 0.088388347648318447f;  // sqrt(1/128)
    const float tk = 0.125f;                 // sqrt(2/128)
    float acc = s0 * t0;
    #pragma unroll 4
    for (int k = 1; k < 64; ++k) {
        float a = cospif((float)((2 * h + 1) * k) * (1.0f / 128.0f));
        float b = cospif((float)((2 * n + 1) * k) * (1.0f / 256.0f));
        acc = fmaf(sk * tk * a, b, acc);
    }
    _Float16 hi = (_Float16)acc;
    _Float16 lo = (_Float16)(acc - (float)hi);
    const int j = n >> 4;
    const int lane = (n & 15) + 16 * ((h >> 3) & 3);
    const int kk = h >> 5;
    const int t = h & 7;
    const int base = ((j * 2 + kk) * 2) * 512 + lane * 8 + t;
    uf[base] = hi;         // hl = 0
    uf[base + 512] = lo;   // hl = 1
}

// ---------------------------------------------------------------------------
// One block = one (b,c) slice. 256 threads = 4 waves.
// Stage 1: R[h][m] = sum_w X[h][w] * U[m][w]   (wave wid owns h-tile wid)
// Stage 2: out[n][m] = sum_h U[n][h] * R[h][m] (wave wid owns n-tiles 2wid,2wid+1)
// LDS: sRh/sRl [128][72] fp16 (pad 8 -> 2-way banks, 16B-aligned b128 reads),
//      sOutW[4][16*132] fp32 per-wave store bounce (coalesced dwordx4 stores).
// ---------------------------------------------------------------------------
__global__ __launch_bounds__(256, 2)
void dct_fsr(const float* __restrict__ x, const float* __restrict__ mask,
             const _Float16* __restrict__ uf, float* __restrict__ out) {
    __shared__ _Float16 sRh[128 * 72];
    __shared__ _Float16 sRl[128 * 72];
    __shared__ float sOutW[4][16 * 132];

    const int tid = threadIdx.x;
    const int wid = tid >> 6;
    const int lane = tid & 63;
    const int l15 = lane & 15;
    const int lg = lane >> 4;  // 0..3
    const int slice = blockIdx.x;
    const float mval = mask[slice & 255];

    const f16x8* ufr = (const f16x8*)uf;  // [frag*64 + lane]

    // ---- A-frags for stage 1: X rows (16*wid + l15), 8 contiguous w per lane ----
    const float* xp = x + (size_t)slice * 4096 + (16 * wid + l15) * 64 + 8 * lg;
    const float4 xa = *(const float4*)xp;          // kk=0, t=0..3
    const float4 xb = *(const float4*)(xp + 4);    // kk=0, t=4..7
    const float4 xc = *(const float4*)(xp + 32);   // kk=1, t=0..3
    const float4 xd = *(const float4*)(xp + 36);   // kk=1, t=4..7

    f16x8 ah0, al0, ah1, al1;
#define SPLIT(H, L, E, V)                      \
    {                                          \
        float y_ = (V) * mval;                 \
        _Float16 h_ = (_Float16)y_;            \
        H[E] = h_;                             \
        L[E] = (_Float16)(y_ - (float)h_);     \
    }
    SPLIT(ah0, al0, 0, xa.x) SPLIT(ah0, al0, 1, xa.y)
    SPLIT(ah0, al0, 2, xa.z) SPLIT(ah0, al0, 3, xa.w)
    SPLIT(ah0, al0, 4, xb.x) SPLIT(ah0, al0, 5, xb.y)
    SPLIT(ah0, al0, 6, xb.z) SPLIT(ah0, al0, 7, xb.w)
    SPLIT(ah1, al1, 0, xc.x) SPLIT(ah1, al1, 1, xc.y)
    SPLIT(ah1, al1, 2, xc.z) SPLIT(ah1, al1, 3, xc.w)
    SPLIT(ah1, al1, 4, xd.x) SPLIT(ah1, al1, 5, xd.y)
    SPLIT(ah1, al1, 6, xd.z) SPLIT(ah1, al1, 7, xd.w)
#undef SPLIT

    // ---- stage 1: per m-tile j, D = X_tile * U^T_tile, 3 passes ----
    #pragma unroll
    for (int j = 0; j < 8; ++j) {
        const f16x8 bh0 = ufr[((j * 2 + 0) * 2 + 0) * 64 + lane];
        const f16x8 bl0 = ufr[((j * 2 + 0) * 2 + 1) * 64 + lane];
        const f16x8 bh1 = ufr[((j * 2 + 1) * 2 + 0) * 64 + lane];
        const f16x8 bl1 = ufr[((j * 2 + 1) * 2 + 1) * 64 + lane];
        f32x4 acc = {0.f, 0.f, 0.f, 0.f};
        acc = MFMA16(ah0, bh0, acc);
        acc = MFMA16(ah1, bh1, acc);
        acc = MFMA16(ah0, bl0, acc);
        acc = MFMA16(ah1, bl1, acc);
        acc = MFMA16(al0, bh0, acc);
        acc = MFMA16(al1, bh1, acc);
        // D frag: col m = 16j+l15, rows h = 16*wid + 4*lg + r  -> sR[m][h]
        const int m = 16 * j + l15;
        const int h0 = 16 * wid + 4 * lg;
        f16x4 rh, rl;
        #pragma unroll
        for (int r = 0; r < 4; ++r) {
            const float vv = acc[r];
            const _Float16 hi = (_Float16)vv;
            rh[r] = hi;
            rl[r] = (_Float16)(vv - (float)hi);
        }
        *(f16x4*)&sRh[m * 72 + h0] = rh;
        *(f16x4*)&sRl[m * 72 + h0] = rl;
    }
    __syncthreads();

    // ---- stage 2: out tiles (n-tile ig = 2*wid+i, m-tile j) ----
    f16x8 Ah[2][2], Al[2][2];
    #pragma unroll
    for (int i = 0; i < 2; ++i) {
        const int ig = 2 * wid + i;
        #pragma unroll
        for (int kk = 0; kk < 2; ++kk) {
            Ah[i][kk] = ufr[((ig * 2 + kk) * 2 + 0) * 64 + lane];
            Al[i][kk] = ufr[((ig * 2 + kk) * 2 + 1) * 64 + lane];
        }
    }

    f32x4 acc2[2][8];
    #pragma unroll
    for (int i = 0; i < 2; ++i)
        #pragma unroll
        for (int j = 0; j < 8; ++j)
            acc2[i][j] = (f32x4){0.f, 0.f, 0.f, 0.f};

    #pragma unroll
    for (int j = 0; j < 8; ++j) {
        const int m = 16 * j + l15;
        const f16x8 bh0 = *(const f16x8*)&sRh[m * 72 + 0 + 8 * lg];
        const f16x8 bh1 = *(const f16x8*)&sRh[m * 72 + 32 + 8 * lg];
        const f16x8 bl0 = *(const f16x8*)&sRl[m * 72 + 0 + 8 * lg];
        const f16x8 bl1 = *(const f16x8*)&sRl[m * 72 + 32 + 8 * lg];
        #pragma unroll
        for (int i = 0; i < 2; ++i) {
            f32x4 a = acc2[i][j];
            a = MFMA16(Ah[i][0], bh0, a);
            a = MFMA16(Ah[i][1], bh1, a);
            a = MFMA16(Ah[i][0], bl0, a);
            a = MFMA16(Ah[i][1], bl1, a);
            a = MFMA16(Al[i][0], bh0, a);
            a = MFMA16(Al[i][1], bh1, a);
            acc2[i][j] = a;
        }
    }

    // ---- epilogue: per-wave LDS bounce -> fully coalesced dwordx4 stores ----
    float* og = out + (size_t)slice * 16384;
    float* sw = sOutW[wid];
    #pragma unroll
    for (int i = 0; i < 2; ++i) {
        const int ig = 2 * wid + i;
        #pragma unroll
        for (int j = 0; j < 8; ++j) {
            const int mc = 16 * j + l15;
            #pragma unroll
            for (int r = 0; r < 4; ++r)
                sw[(4 * lg + r) * 132 + mc] = acc2[i][j][r];
        }
        // per-wave private buffer: DS ops are in-order within a wave
        #pragma unroll
        for (int it = 0; it < 8; ++it) {
            const int c = lane + 64 * it;
            const int row = c >> 5;        // 0..15
            const int m4 = (c & 31) * 4;   // 0..124
            const float4 v = *(const float4*)&sw[row * 132 + m4];
            *(float4*)&og[(size_t)(16 * ig + row) * 128 + m4] = v;
        }
    }
}

extern "C" void kernel_launch(void* const* d_in, const int* in_sizes, int n_in,
                              void* d_out, int out_size, void* d_ws, size_t ws_size,
                              hipStream_t stream) {
    const float* x = (const float*)d_in[0];      // [16,256,64,64] fp32
    const float* mask = (const float*)d_in[1];   // [1,256,1,1] fp32
    float* out = (float*)d_out;                  // [16,256,128,128] fp32
    _Float16* uf = (_Float16*)d_ws;              // 16384 halfs = 32KB

    build_ut<<<32, 256, 0, stream>>>(uf);
    dct_fsr<<<NSLICES, 256, 0, stream>>>(x, mask, uf, out);
}